// Round 10
// baseline (513.726 us; speedup 1.0000x reference)
//
#include <hip/hip_runtime.h>
#include <hip/hip_bf16.h>
#include <cstdint>

#define NHEAD 16
#define ORDERS 4

typedef short short8 __attribute__((ext_vector_type(8)));
typedef float f32x4 __attribute__((ext_vector_type(4)));

__device__ __forceinline__ unsigned short f32_to_bf16_rtn(float f) {
  union { float f; unsigned u; } v; v.f = f;
  unsigned r = v.u + 0x7FFFu + ((v.u >> 16) & 1u);
  return (unsigned short)(r >> 16);
}

// packed f32x2 -> bf16x2 RNE (v_cvt_pk_bf16_f32); .x lands in low 16 bits
__device__ __forceinline__ unsigned pack2(float lo, float hi) {
  __hip_bfloat162 h = __float22bfloat162_rn(float2{lo, hi});
  return *reinterpret_cast<unsigned*>(&h);
}

typedef __attribute__((address_space(1))) void gvoid;
typedef __attribute__((address_space(3))) void svoid;
__device__ __forceinline__ void gload_lds16(const void* g, void* l) {
  // LDS dest = base + lane*16 (wave-uniform base); global src is per-lane
  __builtin_amdgcn_global_load_lds((gvoid*)g, (svoid*)l, 16, 0, 0);
}

// ====== weff kernel: block (h, 64-col chunk c) computes M_h then W_eff ======
__global__ __launch_bounds__(256) void weff_kernel(
    const float* __restrict__ A, const float* __restrict__ t_ptr,
    const float* __restrict__ W, const float* __restrict__ bvec,
    unsigned short* __restrict__ Weff, float* __restrict__ beff) {
  __shared__ float Ah[64 * 65];  // reused as Mh (stride 64) after the orders
  __shared__ float T0[64 * 64];
  __shared__ float T1[64 * 64];

  const int tid = threadIdx.x;
  const int h = blockIdx.x >> 4;
  const int c = blockIdx.x & 15;
  const int d = tid & 63;
  const int ig = tid >> 6;

  float wreg[16];
  #pragma unroll
  for (int r = 0; r < 16; ++r)
    wreg[r] = W[(size_t)(h * 64 + ig * 16 + r) * 1024 + c * 64 + d];

  const float t = t_ptr[0];
  const int i = tid >> 2;
  const int jq = (tid & 3) << 4;

  for (int r = 0; r < 16; ++r) {
    int idx = tid + 256 * r;
    Ah[(idx >> 6) * 65 + (idx & 63)] = A[h * 4096 + idx];
  }
  float ms[16];
  #pragma unroll
  for (int cc = 0; cc < 16; ++cc) {
    float e = (i == jq + cc) ? 1.0f : 0.0f;
    T0[i * 64 + jq + cc] = e;
    ms[cc] = e;
  }
  __syncthreads();

  float* Tc = T0;
  float* Tn = T1;
  for (int k = 1; k <= ORDERS; ++k) {
    float scale = t / (float)k;
    float acc[16];
    #pragma unroll
    for (int cc = 0; cc < 16; ++cc) acc[cc] = 0.f;
    for (int l = 0; l < 64; ++l) {
      float a = Ah[i * 65 + l];
      float4 t0 = *(const float4*)&Tc[l * 64 + jq];
      float4 t1 = *(const float4*)&Tc[l * 64 + jq + 4];
      float4 t2 = *(const float4*)&Tc[l * 64 + jq + 8];
      float4 t3 = *(const float4*)&Tc[l * 64 + jq + 12];
      acc[0] += a * t0.x;  acc[1] += a * t0.y;  acc[2] += a * t0.z;  acc[3] += a * t0.w;
      acc[4] += a * t1.x;  acc[5] += a * t1.y;  acc[6] += a * t1.z;  acc[7] += a * t1.w;
      acc[8] += a * t2.x;  acc[9] += a * t2.y;  acc[10] += a * t2.z; acc[11] += a * t2.w;
      acc[12] += a * t3.x; acc[13] += a * t3.y; acc[14] += a * t3.z; acc[15] += a * t3.w;
    }
    #pragma unroll
    for (int cc = 0; cc < 16; ++cc) { acc[cc] *= scale; ms[cc] += acc[cc]; }
    #pragma unroll
    for (int u = 0; u < 4; ++u) {
      float4 v = {acc[u * 4], acc[u * 4 + 1], acc[u * 4 + 2], acc[u * 4 + 3]};
      *(float4*)&Tn[i * 64 + jq + u * 4] = v;
    }
    __syncthreads();
    float* tmp = Tc; Tc = Tn; Tn = tmp;
  }

  float* Mh = Ah;
  #pragma unroll
  for (int u = 0; u < 4; ++u) {
    float4 v = {ms[u * 4], ms[u * 4 + 1], ms[u * 4 + 2], ms[u * 4 + 3]};
    *(float4*)&Mh[i * 64 + jq + u * 4] = v;
  }
  float* Wc = T0;
  #pragma unroll
  for (int r = 0; r < 16; ++r) Wc[(ig * 16 + r) * 64 + d] = wreg[r];
  __syncthreads();

  #pragma unroll
  for (int ii = 0; ii < 16; ++ii) {
    int i2 = ig * 16 + ii;
    float acc = 0.f;
    #pragma unroll
    for (int j = 0; j < 64; ++j) acc += Mh[i2 * 64 + j] * Wc[j * 64 + d];
    Weff[(size_t)(h * 64 + i2) * 1024 + c * 64 + d] = f32_to_bf16_rtn(acc);
  }
  if (c == 0 && tid < 64) {
    float acc = 0.f;
    for (int j = 0; j < 64; ++j) acc += Mh[tid * 64 + j] * bvec[h * 64 + j];
    beff[h * 64 + tid] = acc;
  }
}

// ======= GEMM: out = bf16(X) @ Weff^T + beff; A f32->reg->cvt, depth-2 =======
// 128x128x64 tile, 4 waves. A: per-lane fragment loads from X with TWO named
// reg sets (even/odd bodies, static indexing) so every vmcnt waits only on
// loads issued ONE FULL BODY earlier (R9 bug fixed). B: gload_lds w16 +
// XOR-swizzle dbuf (R4-proven). vmcnt(20) = keep {A(t+2)16, B(t+1)4}.
#define CSTR 132  // padded f32 stride for epilogue staging

__global__ __launch_bounds__(256, 2) void gemm_kernel(
    const float* __restrict__ X, const unsigned short* __restrict__ Wf,
    const float* __restrict__ beff, float* __restrict__ Out) {
  __shared__ __align__(16) unsigned short Bs[2 * 8192];  // 32 KB (B dbuf only)

  const int wg = blockIdx.x;
  const int swz = (wg & 7) * 256 + (wg >> 3);  // 2048 % 8 == 0: bijective
  const int R = (swz >> 3) * 128;
  const int C = (swz & 7) * 128;

  const int tid = threadIdx.x;
  const int lane = tid & 63;
  const int wave = tid >> 6;
  const int wm = wave >> 1;
  const int wn = wave & 1;
  const int frow = lane & 15;
  const int fkg = lane >> 4;

  f32x4 acc[4][4];
  #pragma unroll
  for (int mi = 0; mi < 4; ++mi)
    #pragma unroll
    for (int ni = 0; ni < 4; ++ni) acc[mi][ni] = (f32x4){0.f, 0.f, 0.f, 0.f};

  // ---- B staging (R4-proven): pre-swizzled source, linear gload_lds dest
  const int lr = lane >> 3;
  const int lc = lane & 7;
  const int scol = ((lc ^ lr) << 3);
  const unsigned short* Bsrc = Wf + (size_t)(C + wave * 32 + lr) * 1024 + scol;
  auto stageB = [&](int kt, int bufSel) {  // 4 gload_lds per wave
    char* Bd = (char*)Bs + bufSel * 16384 + wave * 4096;
    const int kb = kt * 64;
    #pragma unroll
    for (int i = 0; i < 4; ++i)
      gload_lds16(Bsrc + (size_t)(i * 8) * 1024 + kb, Bd + i * 1024);
  };

  // ---- A per-lane fragment loads (fragment layout == linear LDS layout)
  const float* Abase = X + (size_t)(R + wm * 64 + frow) * 1024 + fkg * 8;
  float4 fA0[16], fA1[16];
  auto loadA = [&](int kt, float4 (&fa)[16]) {  // 16 dwordx4 per lane
    #pragma unroll
    for (int mi = 0; mi < 4; ++mi)
      #pragma unroll
      for (int kk = 0; kk < 2; ++kk) {
        const float* p = Abase + (size_t)(mi * 16) * 1024 + kt * 64 + kk * 32;
        fa[(mi * 2 + kk) * 2] = *(const float4*)p;
        fa[(mi * 2 + kk) * 2 + 1] = *(const float4*)(p + 4);
      }
  };
  short8 afr[4][2];
  auto cvtA = [&](const float4 (&fa)[16]) {  // 32 cvt_pk
    #pragma unroll
    for (int mi = 0; mi < 4; ++mi)
      #pragma unroll
      for (int kk = 0; kk < 2; ++kk) {
        int f = (mi * 2 + kk) * 2;
        union { unsigned u[4]; short8 s; } cv;
        cv.u[0] = pack2(fa[f].x, fa[f].y);
        cv.u[1] = pack2(fa[f].z, fa[f].w);
        cv.u[2] = pack2(fa[f + 1].x, fa[f + 1].y);
        cv.u[3] = pack2(fa[f + 1].z, fa[f + 1].w);
        afr[mi][kk] = cv.s;
      }
  };
  auto compute = [&](const unsigned short* B) {  // ds_read frags + 32 MFMA
    short8 bfr[4][2];
    #pragma unroll
    for (int ni = 0; ni < 4; ++ni) {
      int br = wn * 64 + ni * 16 + frow;
      #pragma unroll
      for (int kk = 0; kk < 2; ++kk) {
        int slot = (kk * 4 + fkg) ^ (br & 7);
        bfr[ni][kk] = *(const short8*)&B[br * 64 + slot * 8];
      }
    }
    asm volatile("s_waitcnt lgkmcnt(0)" ::: "memory");
    __builtin_amdgcn_sched_barrier(0);
    __builtin_amdgcn_s_setprio(1);
    #pragma unroll
    for (int mi = 0; mi < 4; ++mi)
      #pragma unroll
      for (int ni = 0; ni < 4; ++ni)
        #pragma unroll
        for (int kk = 0; kk < 2; ++kk)
          acc[mi][ni] = __builtin_amdgcn_mfma_f32_16x16x32_bf16(
              afr[mi][kk], bfr[ni][kk], acc[mi][ni], 0, 0, 0);
    __builtin_amdgcn_s_setprio(0);
  };

  // Prologue: A(0)16, A(1)16, B(0)4 in flight; drain A(0) only.
  loadA(0, fA0);
  loadA(1, fA1);
  stageB(0, 0);
  __builtin_amdgcn_sched_barrier(0);
  asm volatile("s_waitcnt vmcnt(20)" ::: "memory");
  __builtin_amdgcn_sched_barrier(0);

  #pragma unroll 1
  for (int j = 0; j < 8; ++j) {
    // ======== even tile 2j: A in fA0, B in buf0 ========
    cvtA(fA0);                           // A(2j): drained one body ago
    if (j < 7) loadA(2 * j + 2, fA0);    // reuse fA0 (WAR-safe, in-order)
    stageB(2 * j + 1, 1);                // buf1 (readers done: prev odd barrier)
    __builtin_amdgcn_sched_barrier(0);
    // Drain {A(2j+1), B(2j)} (issued last body); keep {A(2j+2), B(2j+1)}.
    if (j < 7) asm volatile("s_waitcnt vmcnt(20)" ::: "memory");
    else       asm volatile("s_waitcnt vmcnt(4)" ::: "memory");  // keep B(15)
    __builtin_amdgcn_sched_barrier(0);
    __builtin_amdgcn_s_barrier();        // B(2j) visible to all waves
    compute(Bs);
    __builtin_amdgcn_s_barrier();        // buf0 reads done -> reusable

    // ======== odd tile 2j+1: A in fA1, B in buf1 ========
    cvtA(fA1);                           // A(2j+1): drained by even body wait
    if (j < 7) {
      loadA(2 * j + 3, fA1);
      stageB(2 * j + 2, 0);              // buf0 (readers done: barrier above)
    }
    __builtin_amdgcn_sched_barrier(0);
    // Drain {A(2j+2), B(2j+1)}; keep {A(2j+3), B(2j+2)}.
    if (j < 7) asm volatile("s_waitcnt vmcnt(20)" ::: "memory");
    else       asm volatile("s_waitcnt vmcnt(0)" ::: "memory");
    __builtin_amdgcn_sched_barrier(0);
    __builtin_amdgcn_s_barrier();        // B(2j+1) visible to all waves
    compute(Bs + 8192);
    __builtin_amdgcn_s_barrier();        // buf1 reads done -> reusable
  }
  __syncthreads();

  // Epilogue: stage 32x128 f32 tile through LDS -> full-line float4 stores
  float* Cs = (float*)Bs;  // 32*132*4 = 16896 B <= 32 KB
  const int c4 = (tid & 31) << 2;
  float4 bb = *(const float4*)&beff[C + c4];
  #pragma unroll
  for (int mi = 0; mi < 4; ++mi) {
    #pragma unroll
    for (int ni = 0; ni < 4; ++ni) {
      int col = wn * 64 + ni * 16 + frow;
      #pragma unroll
      for (int reg = 0; reg < 4; ++reg)
        Cs[(wm * 16 + fkg * 4 + reg) * CSTR + col] = acc[mi][ni][reg];
    }
    __syncthreads();
    #pragma unroll
    for (int it = 0; it < 4; ++it) {
      int rloc = it * 8 + (tid >> 5);
      float4 v = *(const float4*)&Cs[rloc * CSTR + c4];
      v.x += bb.x; v.y += bb.y; v.z += bb.z; v.w += bb.w;
      int grow = R + (rloc >> 4) * 64 + mi * 16 + (rloc & 15);
      *(float4*)(Out + (size_t)grow * 1024 + C + c4) = v;
    }
    __syncthreads();
  }
}

extern "C" void kernel_launch(void* const* d_in, const int* in_sizes, int n_in,
                              void* d_out, int out_size, void* d_ws, size_t ws_size,
                              hipStream_t stream) {
  const float* x = (const float*)d_in[0];
  const float* t = (const float*)d_in[1];
  const float* W = (const float*)d_in[2];
  const float* b = (const float*)d_in[3];
  const float* A = (const float*)d_in[4];
  float* out = (float*)d_out;

  char* ws = (char*)d_ws;
  unsigned short* Weff = (unsigned short*)ws;  // 2 MB @ 0
  float* beff = (float*)(ws + (2 << 20));      // 4 KB @ 2 MB

  weff_kernel<<<256, 256, 0, stream>>>(A, t, W, b, Weff, beff);
  gemm_kernel<<<2048, 256, 0, stream>>>(x, Weff, beff, out);
}

// Round 14
// 156.393 us; speedup vs baseline: 3.2848x; 3.2848x over previous
//
#include <hip/hip_runtime.h>
#include <hip/hip_bf16.h>
#include <cstdint>

#define NHEAD 16
#define ORDERS 4

typedef short short8 __attribute__((ext_vector_type(8)));
typedef float f32x4 __attribute__((ext_vector_type(4)));

__device__ __forceinline__ unsigned short f32_to_bf16_rtn(float f) {
  union { float f; unsigned u; } v; v.f = f;
  unsigned r = v.u + 0x7FFFu + ((v.u >> 16) & 1u);
  return (unsigned short)(r >> 16);
}

// packed f32x2 -> bf16x2 RNE (v_cvt_pk_bf16_f32); .x lands in low 16 bits
__device__ __forceinline__ unsigned pack2(float lo, float hi) {
  __hip_bfloat162 h = __float22bfloat162_rn(float2{lo, hi});
  return *reinterpret_cast<unsigned*>(&h);
}

typedef __attribute__((address_space(1))) void gvoid;
typedef __attribute__((address_space(3))) void svoid;
__device__ __forceinline__ void gload_lds16(const void* g, void* l) {
  // LDS dest = base + lane*16 (wave-uniform base); global src is per-lane
  __builtin_amdgcn_global_load_lds((gvoid*)g, (svoid*)l, 16, 0, 0);
}

// ====== weff kernel: block (h, 64-col chunk c) computes M_h then W_eff ======
__global__ __launch_bounds__(256) void weff_kernel(
    const float* __restrict__ A, const float* __restrict__ t_ptr,
    const float* __restrict__ W, const float* __restrict__ bvec,
    unsigned short* __restrict__ Weff, float* __restrict__ beff) {
  __shared__ float Ah[64 * 65];  // reused as Mh (stride 64) after the orders
  __shared__ float T0[64 * 64];
  __shared__ float T1[64 * 64];

  const int tid = threadIdx.x;
  const int h = blockIdx.x >> 4;
  const int c = blockIdx.x & 15;
  const int d = tid & 63;
  const int ig = tid >> 6;

  float wreg[16];
  #pragma unroll
  for (int r = 0; r < 16; ++r)
    wreg[r] = W[(size_t)(h * 64 + ig * 16 + r) * 1024 + c * 64 + d];

  const float t = t_ptr[0];
  const int i = tid >> 2;
  const int jq = (tid & 3) << 4;

  for (int r = 0; r < 16; ++r) {
    int idx = tid + 256 * r;
    Ah[(idx >> 6) * 65 + (idx & 63)] = A[h * 4096 + idx];
  }
  float ms[16];
  #pragma unroll
  for (int cc = 0; cc < 16; ++cc) {
    float e = (i == jq + cc) ? 1.0f : 0.0f;
    T0[i * 64 + jq + cc] = e;
    ms[cc] = e;
  }
  __syncthreads();

  float* Tc = T0;
  float* Tn = T1;
  for (int k = 1; k <= ORDERS; ++k) {
    float scale = t / (float)k;
    float acc[16];
    #pragma unroll
    for (int cc = 0; cc < 16; ++cc) acc[cc] = 0.f;
    for (int l = 0; l < 64; ++l) {
      float a = Ah[i * 65 + l];
      float4 t0 = *(const float4*)&Tc[l * 64 + jq];
      float4 t1 = *(const float4*)&Tc[l * 64 + jq + 4];
      float4 t2 = *(const float4*)&Tc[l * 64 + jq + 8];
      float4 t3 = *(const float4*)&Tc[l * 64 + jq + 12];
      acc[0] += a * t0.x;  acc[1] += a * t0.y;  acc[2] += a * t0.z;  acc[3] += a * t0.w;
      acc[4] += a * t1.x;  acc[5] += a * t1.y;  acc[6] += a * t1.z;  acc[7] += a * t1.w;
      acc[8] += a * t2.x;  acc[9] += a * t2.y;  acc[10] += a * t2.z; acc[11] += a * t2.w;
      acc[12] += a * t3.x; acc[13] += a * t3.y; acc[14] += a * t3.z; acc[15] += a * t3.w;
    }
    #pragma unroll
    for (int cc = 0; cc < 16; ++cc) { acc[cc] *= scale; ms[cc] += acc[cc]; }
    #pragma unroll
    for (int u = 0; u < 4; ++u) {
      float4 v = {acc[u * 4], acc[u * 4 + 1], acc[u * 4 + 2], acc[u * 4 + 3]};
      *(float4*)&Tn[i * 64 + jq + u * 4] = v;
    }
    __syncthreads();
    float* tmp = Tc; Tc = Tn; Tn = tmp;
  }

  float* Mh = Ah;
  #pragma unroll
  for (int u = 0; u < 4; ++u) {
    float4 v = {ms[u * 4], ms[u * 4 + 1], ms[u * 4 + 2], ms[u * 4 + 3]};
    *(float4*)&Mh[i * 64 + jq + u * 4] = v;
  }
  float* Wc = T0;
  #pragma unroll
  for (int r = 0; r < 16; ++r) Wc[(ig * 16 + r) * 64 + d] = wreg[r];
  __syncthreads();

  #pragma unroll
  for (int ii = 0; ii < 16; ++ii) {
    int i2 = ig * 16 + ii;
    float acc = 0.f;
    #pragma unroll
    for (int j = 0; j < 64; ++j) acc += Mh[i2 * 64 + j] * Wc[j * 64 + d];
    Weff[(size_t)(h * 64 + i2) * 1024 + c * 64 + d] = f32_to_bf16_rtn(acc);
  }
  if (c == 0 && tid < 64) {
    float acc = 0.f;
    for (int j = 0; j < 64; ++j) acc += Mh[tid * 64 + j] * bvec[h * 64 + j];
    beff[h * 64 + tid] = acc;
  }
}

// ====== GEMM single-pass: out = bf16(X) @ Weff^T + beff ======================
// R13 design with the B-dbuf STRIDE BUG fixed: a B tile is 128x64 bf16 =
// 16384 B (not 8192). LDS map: A buf0 @0, A buf1 @16384, B buf0 @32768,
// B buf1 @49152 — total 65536 B. Schedule: R4/R7 counted-vmcnt dbuf.
// B: gload_lds + XOR swizzle (proven). A: cooperative reg-staging with
// one-iteration lead; cvt_pk + swizzled ds_write during compute phase.
#define CSTR 132  // padded f32 stride for epilogue staging

__global__ __launch_bounds__(256, 2) void gemm_kernel(
    const float* __restrict__ X, const unsigned short* __restrict__ Wf,
    const float* __restrict__ beff, float* __restrict__ Out) {
  __shared__ __align__(16) char smem[65536];

  const int wg = blockIdx.x;
  const int swz = (wg & 7) * 256 + (wg >> 3);  // 2048 % 8 == 0: bijective
  const int R = (swz >> 3) * 128;
  const int C = (swz & 7) * 128;

  const int tid = threadIdx.x;
  const int lane = tid & 63;
  const int wave = tid >> 6;
  const int wm = wave >> 1;
  const int wn = wave & 1;
  const int frow = lane & 15;
  const int fkg = lane >> 4;

  f32x4 acc[4][4];
  #pragma unroll
  for (int mi = 0; mi < 4; ++mi)
    #pragma unroll
    for (int ni = 0; ni < 4; ++ni) acc[mi][ni] = (f32x4){0.f, 0.f, 0.f, 0.f};

  // ---- B staging (R4-proven): pre-swizzled global source, linear LDS dest
  const int lr = lane >> 3;
  const int lc = lane & 7;
  const unsigned short* Bsrc = Wf + (size_t)(C + wave * 32 + lr) * 1024 + ((lc ^ lr) << 3);
  auto stageB = [&](int kt, int bufSel) {  // 4 gload_lds per wave
    char* Bd = smem + 32768 + bufSel * 16384 + wave * 4096;  // FIX: stride 16384
    const int kb = kt * 64;
    #pragma unroll
    for (int i = 0; i < 4; ++i)
      gload_lds16(Bsrc + (size_t)(i * 8) * 1024 + kb, Bd + i * 1024);
  };

  // ---- A reg-staging: thread covers rows arw+16i (i<8), f32 cols q*4..+4
  const int arw = tid >> 4;
  const int q = tid & 15;
  const float* Asrc = X + (size_t)(R + arw) * 1024 + q * 4;
  auto loadA = [&](int kt, float4 (&av)[8]) {  // 8 global dwordx4 per thread
    const float* p = Asrc + kt * 64;
    #pragma unroll
    for (int i = 0; i < 8; ++i)
      av[i] = *(const float4*)(p + (size_t)i * 16 * 1024);
  };
  // cvt + swizzled ds_write: byte = row*128 + ((q/2 ^ row&7)<<4) + (q&1)*8
  const int awoff = ((q >> 1) ^ (arw & 7)) * 16 + (q & 1) * 8;
  auto cvtWriteA = [&](const float4 (&av)[8], int bufSel) {
    char* Ab = smem + bufSel * 16384;
    #pragma unroll
    for (int i = 0; i < 8; ++i) {
      uint2 wv;
      wv.x = pack2(av[i].x, av[i].y);
      wv.y = pack2(av[i].z, av[i].w);
      *(uint2*)(Ab + (arw + i * 16) * 128 + awoff) = wv;
    }
  };

  float4 avE[8], avO[8];

  // Prologue: A(0)->avE, B(0), A(1)->avO in flight; drain A(0); write buf0.
  loadA(0, avE);
  stageB(0, 0);
  loadA(1, avO);
  __builtin_amdgcn_sched_barrier(0);
  asm volatile("s_waitcnt vmcnt(12)" ::: "memory");  // A(0) arrived
  __builtin_amdgcn_sched_barrier(0);
  cvtWriteA(avE, 0);
  asm volatile("s_waitcnt lgkmcnt(0)" ::: "memory");  // A(0) committed to LDS
  __builtin_amdgcn_sched_barrier(0);

  // Per-iter body. Steady: drain {B(kt), A(kt+1)} = vmcnt(12); tails 4/0.
  #define GEMM_BODY(KT, AVCVT, AVLOAD)                                         \
  {                                                                            \
    constexpr int kt = (KT);                                                   \
    if (kt + 1 < 16) stageB(kt + 1, (kt + 1) & 1);                             \
    if (kt + 2 < 16) loadA(kt + 2, AVLOAD);                                    \
    __builtin_amdgcn_sched_barrier(0);                                         \
    if (kt <= 13)                                                              \
      asm volatile("s_waitcnt vmcnt(12)" ::: "memory");                        \
    else if (kt == 14)                                                         \
      asm volatile("s_waitcnt vmcnt(4)" ::: "memory");                         \
    else                                                                       \
      asm volatile("s_waitcnt vmcnt(0)" ::: "memory");                         \
    __builtin_amdgcn_sched_barrier(0);                                         \
    __builtin_amdgcn_s_barrier(); /* buf[kt&1] complete for all waves */       \
    const unsigned short* As = (const unsigned short*)(smem + (kt & 1) * 16384); \
    const unsigned short* Bb =                                                 \
        (const unsigned short*)(smem + 32768 + (kt & 1) * 16384);              \
    short8 afr[4][2], bfr[4][2];                                               \
    _Pragma("unroll") for (int mi = 0; mi < 4; ++mi) {                         \
      int ar = wm * 64 + mi * 16 + frow;                                       \
      _Pragma("unroll") for (int kk = 0; kk < 2; ++kk) {                       \
        int slot = (kk * 4 + fkg) ^ (ar & 7);                                  \
        afr[mi][kk] = *(const short8*)&As[ar * 64 + slot * 8];                 \
      }                                                                        \
    }                                                                          \
    _Pragma("unroll") for (int ni = 0; ni < 4; ++ni) {                         \
      int br = wn * 64 + ni * 16 + frow;                                       \
      _Pragma("unroll") for (int kk = 0; kk < 2; ++kk) {                       \
        int slot = (kk * 4 + fkg) ^ (br & 7);                                  \
        bfr[ni][kk] = *(const short8*)&Bb[br * 64 + slot * 8];                 \
      }                                                                        \
    }                                                                          \
    if (kt + 1 < 16) cvtWriteA(AVCVT, (kt + 1) & 1);                           \
    asm volatile("s_waitcnt lgkmcnt(0)" ::: "memory");                         \
    __builtin_amdgcn_sched_barrier(0);                                         \
    __builtin_amdgcn_s_barrier(); /* reads+writes of this phase done */        \
    __builtin_amdgcn_s_setprio(1);                                             \
    _Pragma("unroll") for (int mi = 0; mi < 4; ++mi)                           \
        _Pragma("unroll") for (int ni = 0; ni < 4; ++ni)                       \
            _Pragma("unroll") for (int kk = 0; kk < 2; ++kk)                   \
                acc[mi][ni] = __builtin_amdgcn_mfma_f32_16x16x32_bf16(         \
                    afr[mi][kk], bfr[ni][kk], acc[mi][ni], 0, 0, 0);           \
    __builtin_amdgcn_s_setprio(0);                                             \
  }

  GEMM_BODY(0, avO, avE)   GEMM_BODY(1, avE, avO)
  GEMM_BODY(2, avO, avE)   GEMM_BODY(3, avE, avO)
  GEMM_BODY(4, avO, avE)   GEMM_BODY(5, avE, avO)
  GEMM_BODY(6, avO, avE)   GEMM_BODY(7, avE, avO)
  GEMM_BODY(8, avO, avE)   GEMM_BODY(9, avE, avO)
  GEMM_BODY(10, avO, avE)  GEMM_BODY(11, avE, avO)
  GEMM_BODY(12, avO, avE)  GEMM_BODY(13, avE, avO)
  GEMM_BODY(14, avO, avE)  GEMM_BODY(15, avE, avO)
  #undef GEMM_BODY
  __syncthreads();

  // Epilogue: stage 32x128 f32 tile through LDS -> full-line float4 stores
  float* Cs = (float*)smem;  // 32*132*4 = 16896 B
  const int c4 = (tid & 31) << 2;
  float4 bb = *(const float4*)&beff[C + c4];
  #pragma unroll
  for (int mi = 0; mi < 4; ++mi) {
    #pragma unroll
    for (int ni = 0; ni < 4; ++ni) {
      int col = wn * 64 + ni * 16 + frow;
      #pragma unroll
      for (int reg = 0; reg < 4; ++reg)
        Cs[(wm * 16 + fkg * 4 + reg) * CSTR + col] = acc[mi][ni][reg];
    }
    __syncthreads();
    #pragma unroll
    for (int it = 0; it < 4; ++it) {
      int rloc = it * 8 + (tid >> 5);
      float4 v = *(const float4*)&Cs[rloc * CSTR + c4];
      v.x += bb.x; v.y += bb.y; v.z += bb.z; v.w += bb.w;
      int grow = R + (rloc >> 4) * 64 + mi * 16 + (rloc & 15);
      *(float4*)(Out + (size_t)grow * 1024 + C + c4) = v;
    }
    __syncthreads();
  }
}

extern "C" void kernel_launch(void* const* d_in, const int* in_sizes, int n_in,
                              void* d_out, int out_size, void* d_ws, size_t ws_size,
                              hipStream_t stream) {
  const float* x = (const float*)d_in[0];
  const float* t = (const float*)d_in[1];
  const float* W = (const float*)d_in[2];
  const float* b = (const float*)d_in[3];
  const float* A = (const float*)d_in[4];
  float* out = (float*)d_out;

  char* ws = (char*)d_ws;
  unsigned short* Weff = (unsigned short*)ws;  // 2 MB @ 0
  float* beff = (float*)(ws + (2 << 20));      // 4 KB @ 2 MB

  weff_kernel<<<256, 256, 0, stream>>>(A, t, W, b, Weff, beff);
  gemm_kernel<<<2048, 256, 0, stream>>>(x, Weff, beff, out);
}

// Round 15
// 147.970 us; speedup vs baseline: 3.4718x; 1.0569x over previous
//
#include <hip/hip_runtime.h>
#include <hip/hip_bf16.h>
#include <cstdint>

#define NHEAD 16
#define ORDERS 4

typedef short short8 __attribute__((ext_vector_type(8)));
typedef float f32x4 __attribute__((ext_vector_type(4)));

__device__ __forceinline__ unsigned short f32_to_bf16_rtn(float f) {
  union { float f; unsigned u; } v; v.f = f;
  unsigned r = v.u + 0x7FFFu + ((v.u >> 16) & 1u);
  return (unsigned short)(r >> 16);
}

typedef __attribute__((address_space(1))) void gvoid;
typedef __attribute__((address_space(3))) void svoid;
__device__ __forceinline__ void gload_lds16(const void* g, void* l) {
  // LDS dest = base + lane*16 (wave-uniform base); global src is per-lane
  __builtin_amdgcn_global_load_lds((gvoid*)g, (svoid*)l, 16, 0, 0);
}

// ====== weff kernel: block (h, 64-col chunk c) computes M_h then W_eff ======
// M_h = sum_{k<=4} (tA_h)^k / k! recomputed per block (16x redundant, cheap).
__global__ __launch_bounds__(256) void weff_kernel(
    const float* __restrict__ A, const float* __restrict__ t_ptr,
    const float* __restrict__ W, const float* __restrict__ bvec,
    unsigned short* __restrict__ Weff, float* __restrict__ beff) {
  __shared__ float Ah[64 * 65];  // reused as Mh (stride 64) after the orders
  __shared__ float T0[64 * 64];
  __shared__ float T1[64 * 64];

  const int tid = threadIdx.x;
  const int h = blockIdx.x >> 4;
  const int c = blockIdx.x & 15;
  const int d = tid & 63;
  const int ig = tid >> 6;  // wave id 0..3

  // Prefetch W chunk rows [ig*16,+16) into regs; arrives during M-compute.
  float wreg[16];
  #pragma unroll
  for (int r = 0; r < 16; ++r)
    wreg[r] = W[(size_t)(h * 64 + ig * 16 + r) * 1024 + c * 64 + d];

  const float t = t_ptr[0];
  const int i = tid >> 2;
  const int jq = (tid & 3) << 4;

  for (int r = 0; r < 16; ++r) {
    int idx = tid + 256 * r;
    Ah[(idx >> 6) * 65 + (idx & 63)] = A[h * 4096 + idx];
  }
  float ms[16];
  #pragma unroll
  for (int cc = 0; cc < 16; ++cc) {
    float e = (i == jq + cc) ? 1.0f : 0.0f;
    T0[i * 64 + jq + cc] = e;
    ms[cc] = e;
  }
  __syncthreads();

  float* Tc = T0;
  float* Tn = T1;
  for (int k = 1; k <= ORDERS; ++k) {
    float scale = t / (float)k;
    float acc[16];
    #pragma unroll
    for (int cc = 0; cc < 16; ++cc) acc[cc] = 0.f;
    for (int l = 0; l < 64; ++l) {
      float a = Ah[i * 65 + l];
      float4 t0 = *(const float4*)&Tc[l * 64 + jq];
      float4 t1 = *(const float4*)&Tc[l * 64 + jq + 4];
      float4 t2 = *(const float4*)&Tc[l * 64 + jq + 8];
      float4 t3 = *(const float4*)&Tc[l * 64 + jq + 12];
      acc[0] += a * t0.x;  acc[1] += a * t0.y;  acc[2] += a * t0.z;  acc[3] += a * t0.w;
      acc[4] += a * t1.x;  acc[5] += a * t1.y;  acc[6] += a * t1.z;  acc[7] += a * t1.w;
      acc[8] += a * t2.x;  acc[9] += a * t2.y;  acc[10] += a * t2.z; acc[11] += a * t2.w;
      acc[12] += a * t3.x; acc[13] += a * t3.y; acc[14] += a * t3.z; acc[15] += a * t3.w;
    }
    #pragma unroll
    for (int cc = 0; cc < 16; ++cc) { acc[cc] *= scale; ms[cc] += acc[cc]; }
    #pragma unroll
    for (int u = 0; u < 4; ++u) {
      float4 v = {acc[u * 4], acc[u * 4 + 1], acc[u * 4 + 2], acc[u * 4 + 3]};
      *(float4*)&Tn[i * 64 + jq + u * 4] = v;
    }
    __syncthreads();
    float* tmp = Tc; Tc = Tn; Tn = tmp;
  }

  float* Mh = Ah;  // overwrite Ah with Mh (stride 64)
  #pragma unroll
  for (int u = 0; u < 4; ++u) {
    float4 v = {ms[u * 4], ms[u * 4 + 1], ms[u * 4 + 2], ms[u * 4 + 3]};
    *(float4*)&Mh[i * 64 + jq + u * 4] = v;
  }
  float* Wc = T0;
  #pragma unroll
  for (int r = 0; r < 16; ++r) Wc[(ig * 16 + r) * 64 + d] = wreg[r];
  __syncthreads();

  #pragma unroll
  for (int ii = 0; ii < 16; ++ii) {
    int i2 = ig * 16 + ii;  // wave-uniform -> Mh reads broadcast
    float acc = 0.f;
    #pragma unroll
    for (int j = 0; j < 64; ++j) acc += Mh[i2 * 64 + j] * Wc[j * 64 + d];
    Weff[(size_t)(h * 64 + i2) * 1024 + c * 64 + d] = f32_to_bf16_rtn(acc);
  }
  if (c == 0 && tid < 64) {
    float acc = 0.f;
    for (int j = 0; j < 64; ++j) acc += Mh[tid * 64 + j] * bvec[h * 64 + j];
    beff[h * 64 + tid] = acc;
  }
}

// ------- Convert: X f32 -> bf16 Xb. No LDS -> full occupancy, BW-bound ------
__global__ __launch_bounds__(256) void convert_x_kernel(
    const float* __restrict__ X, unsigned short* __restrict__ Xb, int n8) {
  int idx = blockIdx.x * blockDim.x + threadIdx.x;
  int stride = gridDim.x * blockDim.x;
  for (int i = idx; i < n8; i += stride) {
    float4 a = *(const float4*)(X + (size_t)i * 8);
    float4 b = *(const float4*)(X + (size_t)i * 8 + 4);
    unsigned short t[8] = {f32_to_bf16_rtn(a.x), f32_to_bf16_rtn(a.y),
                           f32_to_bf16_rtn(a.z), f32_to_bf16_rtn(a.w),
                           f32_to_bf16_rtn(b.x), f32_to_bf16_rtn(b.y),
                           f32_to_bf16_rtn(b.z), f32_to_bf16_rtn(b.w)};
    *(uint4*)(Xb + (size_t)i * 8) = *(const uint4*)t;
  }
}

// ------------- GEMM (R4/R7-proven): counted-vmcnt dbuf MFMA, T2+T4 -----------
// 128x128x64 tile, 4 waves, 2x32KB LDS dbuf, gload_lds w16 both operands,
// XOR-swizzled LDS (pre-swizzled source / swizzled ds_read), s_waitcnt
// vmcnt(8): next tile's 8 loads stay in flight across the barrier.
#define CSTR 132  // padded f32 stride for epilogue staging

__global__ __launch_bounds__(256, 2) void gemm_kernel(
    const unsigned short* __restrict__ Xb, const unsigned short* __restrict__ Wf,
    const float* __restrict__ beff, float* __restrict__ Out) {
  __shared__ __align__(16) unsigned short smem[4 * 8192];  // 2 bufs x (A 16K + B 16K)

  const int wg = blockIdx.x;
  const int swz = (wg & 7) * 256 + (wg >> 3);  // 2048 % 8 == 0: bijective
  const int by = swz >> 3;
  const int bx = swz & 7;
  const int R = by * 128;
  const int C = bx * 128;

  const int tid = threadIdx.x;
  const int lane = tid & 63;
  const int wave = tid >> 6;
  const int wm = wave >> 1;
  const int wn = wave & 1;
  const int frow = lane & 15;
  const int fkg = lane >> 4;

  f32x4 acc[4][4];
  #pragma unroll
  for (int mi = 0; mi < 4; ++mi)
    #pragma unroll
    for (int ni = 0; ni < 4; ++ni) acc[mi][ni] = (f32x4){0.f, 0.f, 0.f, 0.f};

  const int lr = lane >> 3;            // row within 8-row group (= row&7)
  const int lc = lane & 7;             // dest 16B slot
  const int scol = ((lc ^ lr) << 3);   // pre-swizzled source col (rule #21)
  const unsigned short* Asrc = Xb + (size_t)(R + wave * 32 + lr) * 1024 + scol;
  const unsigned short* Bsrc = Wf + (size_t)(C + wave * 32 + lr) * 1024 + scol;

  auto stage = [&](int kt) {
    unsigned short* base = smem + (kt & 1) * 16384;
    char* Ad = (char*)(base + wave * 32 * 64);
    char* Bd = (char*)(base + 8192 + wave * 32 * 64);
    const int kb = kt * 64;
    #pragma unroll
    for (int i = 0; i < 4; ++i)
      gload_lds16(Asrc + (size_t)(i * 8) * 1024 + kb, Ad + i * 1024);
    #pragma unroll
    for (int i = 0; i < 4; ++i)
      gload_lds16(Bsrc + (size_t)(i * 8) * 1024 + kb, Bd + i * 1024);
  };

  stage(0);
  for (int kt = 0; kt < 16; ++kt) {
    if (kt < 15) {
      stage(kt + 1);  // 8 loads for tile kt+1 go (and stay) in flight
      asm volatile("s_waitcnt vmcnt(8)" ::: "memory");  // tile kt complete
    } else {
      asm volatile("s_waitcnt vmcnt(0)" ::: "memory");
    }
    __builtin_amdgcn_sched_barrier(0);
    __builtin_amdgcn_s_barrier();  // buf[kt&1] valid for all waves

    const unsigned short* As = smem + (kt & 1) * 16384;
    const unsigned short* Bs = As + 8192;
    short8 afr[4][2], bfr[4][2];
    #pragma unroll
    for (int mi = 0; mi < 4; ++mi) {
      int ar = wm * 64 + mi * 16 + frow;
      #pragma unroll
      for (int kk = 0; kk < 2; ++kk) {
        int slot = (kk * 4 + fkg) ^ (ar & 7);
        afr[mi][kk] = *(const short8*)&As[ar * 64 + slot * 8];
      }
    }
    #pragma unroll
    for (int ni = 0; ni < 4; ++ni) {
      int br = wn * 64 + ni * 16 + frow;
      #pragma unroll
      for (int kk = 0; kk < 2; ++kk) {
        int slot = (kk * 4 + fkg) ^ (br & 7);
        bfr[ni][kk] = *(const short8*)&Bs[br * 64 + slot * 8];
      }
    }
    asm volatile("s_waitcnt lgkmcnt(0)" ::: "memory");  // my reads done
    __builtin_amdgcn_sched_barrier(0);
    __builtin_amdgcn_s_barrier();  // all reads done -> next stage may overwrite

    #pragma unroll
    for (int mi = 0; mi < 4; ++mi)
      #pragma unroll
      for (int ni = 0; ni < 4; ++ni)
        #pragma unroll
        for (int kk = 0; kk < 2; ++kk)
          acc[mi][ni] = __builtin_amdgcn_mfma_f32_16x16x32_bf16(
              afr[mi][kk], bfr[ni][kk], acc[mi][ni], 0, 0, 0);
  }
  __syncthreads();

  // Epilogue: stage 32x128 f32 tile through LDS -> full-line float4 stores
  float* Cs = (float*)smem;  // 32*132*4 = 16896 B
  const int c4 = (tid & 31) << 2;
  float4 bb = *(const float4*)&beff[C + c4];
  #pragma unroll
  for (int mi = 0; mi < 4; ++mi) {
    #pragma unroll
    for (int ni = 0; ni < 4; ++ni) {
      int col = wn * 64 + ni * 16 + frow;
      #pragma unroll
      for (int reg = 0; reg < 4; ++reg)
        Cs[(wm * 16 + fkg * 4 + reg) * CSTR + col] = acc[mi][ni][reg];
    }
    __syncthreads();
    #pragma unroll
    for (int it = 0; it < 4; ++it) {
      int rloc = it * 8 + (tid >> 5);
      float4 v = *(const float4*)&Cs[rloc * CSTR + c4];
      v.x += bb.x; v.y += bb.y; v.z += bb.z; v.w += bb.w;
      int grow = R + (rloc >> 4) * 64 + mi * 16 + (rloc & 15);
      *(float4*)(Out + (size_t)grow * 1024 + C + c4) = v;
    }
    __syncthreads();
  }
}

// ---------------- Fallback GEMM (reg-staged, f32 X) if ws is small -----------
#define LDSS 72
#define CSTRF 136
__global__ __launch_bounds__(256, 2) void gemm_fb(
    const float* __restrict__ X, const unsigned short* __restrict__ Weff,
    const float* __restrict__ beff, float* __restrict__ Out) {
  __shared__ __align__(16) unsigned short As0[128 * LDSS];
  __shared__ __align__(16) unsigned short As1[128 * LDSS];
  __shared__ __align__(16) unsigned short Bs0[128 * LDSS];
  __shared__ __align__(16) unsigned short Bs1[128 * LDSS];
  const int wg = blockIdx.x;
  const int swz = (wg & 7) * 256 + (wg >> 3);
  const int R = (swz >> 3) * 128;
  const int C = (swz & 7) * 128;
  const int tid = threadIdx.x;
  const int lane = tid & 63;
  const int wave = tid >> 6;
  const int wm = wave >> 1, wn = wave & 1;
  const int frow = lane & 15, fkg = lane >> 4;
  f32x4 acc[4][4];
  #pragma unroll
  for (int mi = 0; mi < 4; ++mi)
    #pragma unroll
    for (int ni = 0; ni < 4; ++ni) acc[mi][ni] = (f32x4){0.f, 0.f, 0.f, 0.f};
  const int ar = tid >> 4, akc = (tid & 15) << 2;
  const int bn_ = tid >> 3, bkc = (tid & 7) << 3;
  const float* Xbase = X + (size_t)(R + ar) * 1024 + akc;
  const unsigned short* Wbase = Weff + (size_t)(C + bn_) * 1024 + bkc;
  float4 av[8];
  uint4 bv[4];
  auto loadTile = [&](int kt) {
    const int kb = kt * 64;
    #pragma unroll
    for (int i = 0; i < 8; ++i) av[i] = *(const float4*)(Xbase + (size_t)i * 16 * 1024 + kb);
    #pragma unroll
    for (int i = 0; i < 4; ++i) bv[i] = *(const uint4*)(Wbase + (size_t)i * 32 * 1024 + kb);
  };
  auto writeTile = [&](unsigned short* Asn, unsigned short* Bsn) {
    #pragma unroll
    for (int i = 0; i < 8; ++i) {
      unsigned short tmp[4] = {f32_to_bf16_rtn(av[i].x), f32_to_bf16_rtn(av[i].y),
                               f32_to_bf16_rtn(av[i].z), f32_to_bf16_rtn(av[i].w)};
      *(uint2*)&Asn[(ar + i * 16) * LDSS + akc] = *(const uint2*)tmp;
    }
    #pragma unroll
    for (int i = 0; i < 4; ++i) *(uint4*)&Bsn[(bn_ + i * 32) * LDSS + bkc] = bv[i];
  };
  loadTile(0);
  writeTile(As0, Bs0);
  __syncthreads();
  unsigned short* Asc = As0; unsigned short* Asn = As1;
  unsigned short* Bsc = Bs0; unsigned short* Bsn = Bs1;
  for (int kt = 0; kt < 16; ++kt) {
    if (kt < 15) loadTile(kt + 1);
    short8 afr[4][2], bfr[4][2];
    #pragma unroll
    for (int mi = 0; mi < 4; ++mi)
      #pragma unroll
      for (int kk = 0; kk < 2; ++kk)
        afr[mi][kk] = *(const short8*)&Asc[(wm * 64 + mi * 16 + frow) * LDSS + kk * 32 + fkg * 8];
    #pragma unroll
    for (int ni = 0; ni < 4; ++ni)
      #pragma unroll
      for (int kk = 0; kk < 2; ++kk)
        bfr[ni][kk] = *(const short8*)&Bsc[(wn * 64 + ni * 16 + frow) * LDSS + kk * 32 + fkg * 8];
    #pragma unroll
    for (int mi = 0; mi < 4; ++mi)
      #pragma unroll
      for (int ni = 0; ni < 4; ++ni)
        #pragma unroll
        for (int kk = 0; kk < 2; ++kk)
          acc[mi][ni] = __builtin_amdgcn_mfma_f32_16x16x32_bf16(
              afr[mi][kk], bfr[ni][kk], acc[mi][ni], 0, 0, 0);
    if (kt < 15) writeTile(Asn, Bsn);
    __syncthreads();
    unsigned short* t1 = Asc; Asc = Asn; Asn = t1;
    unsigned short* t2 = Bsc; Bsc = Bsn; Bsn = t2;
  }
  float* Cs = (float*)As0;
  const int c4 = (tid & 31) << 2;
  float4 bb = *(const float4*)&beff[C + c4];
  #pragma unroll
  for (int mi = 0; mi < 4; ++mi) {
    #pragma unroll
    for (int ni = 0; ni < 4; ++ni) {
      int col = wn * 64 + ni * 16 + frow;
      #pragma unroll
      for (int reg = 0; reg < 4; ++reg)
        Cs[(wm * 16 + fkg * 4 + reg) * CSTRF + col] = acc[mi][ni][reg];
    }
    __syncthreads();
    #pragma unroll
    for (int it = 0; it < 4; ++it) {
      int rloc = it * 8 + (tid >> 5);
      float4 v = *(const float4*)&Cs[rloc * CSTRF + c4];
      v.x += bb.x; v.y += bb.y; v.z += bb.z; v.w += bb.w;
      int grow = R + (rloc >> 4) * 64 + mi * 16 + (rloc & 15);
      *(float4*)(Out + (size_t)grow * 1024 + C + c4) = v;
    }
    __syncthreads();
  }
}

extern "C" void kernel_launch(void* const* d_in, const int* in_sizes, int n_in,
                              void* d_out, int out_size, void* d_ws, size_t ws_size,
                              hipStream_t stream) {
  const float* x = (const float*)d_in[0];
  const float* t = (const float*)d_in[1];
  const float* W = (const float*)d_in[2];
  const float* b = (const float*)d_in[3];
  const float* A = (const float*)d_in[4];
  float* out = (float*)d_out;

  char* ws = (char*)d_ws;
  unsigned short* Weff = (unsigned short*)ws;                 // 2 MB @ 0
  float* beff = (float*)(ws + (2 << 20));                     // 4 KB @ 2 MB
  unsigned short* Xb = (unsigned short*)(ws + (4ull << 20));  // 64 MB @ 4 MB

  const size_t need = (4ull << 20) + (64ull << 20);
  weff_kernel<<<256, 256, 0, stream>>>(A, t, W, b, Weff, beff);
  if (ws_size >= need) {
    convert_x_kernel<<<2048, 256, 0, stream>>>(x, Xb, 33554432 / 8);
    gemm_kernel<<<2048, 256, 0, stream>>>(Xb, Weff, beff, out);
  } else {
    gemm_fb<<<2048, 256, 0, stream>>>(x, Weff, beff, out);
  }
}